// Round 12
// baseline (17.842 us; speedup 1.0000x reference)
//
#include <hip/hip_runtime.h>
#include <hip/hip_bf16.h>

#define TD 512
#define SD 128
#define NT 8
#define BATCH 16384
#define BR 64              // rows per block

typedef float f32x4 __attribute__((ext_vector_type(4)));
typedef short s16x8 __attribute__((ext_vector_type(8)));
typedef unsigned short u16;
typedef unsigned long long u64;

__device__ __forceinline__ u16 f2bf(float f) {
    return __builtin_bit_cast(u16, __float2bfloat16(f));   // RNE
}
__device__ __forceinline__ u64 pack4bf(f32x4 v) {
    u16 a[4];
    #pragma unroll
    for (int j = 0; j < 4; ++j) a[j] = f2bf(v[j]);
    return __builtin_bit_cast(u64, *(ushort4*)a);
}
__device__ __forceinline__ void glds16(const void* g, void* l) {
    __builtin_amdgcn_global_load_lds(
        (const __attribute__((address_space(1))) unsigned int*)g,
        (__attribute__((address_space(3))) unsigned int*)l, 16, 0, 0);
}

// prep: logits output + WF = W as MFMA B-fragments in lane order (bf16).
// WF unit u = (cg*16 + kidx)*64 + lane  (16 B each):
//   WF[u][j] = W[kidx*32 + (lane>>4)*8 + j][cg*16 + (lane&15)]
__global__ __launch_bounds__(256) void prep_kernel(
    const float* __restrict__ W, const float* __restrict__ clogits,
    const int* __restrict__ slot, const int* __restrict__ hit,
    u16* __restrict__ WF, float* __restrict__ logits_out)
{
    const int gid = blockIdx.x * 256 + threadIdx.x;   // 0..32767
    {   // logits: 2 threads per row, f32x4 each
        const int row = gid >> 1;
        const int j4 = (gid & 1) * 4;
        f32x4 v = (f32x4){0.f, 0.f, 0.f, 0.f};
        if (hit[row]) v = *(const f32x4*)(clogits + (long)slot[row] * NT + j4);
        *(f32x4*)(logits_out + (long)row * NT + j4) = v;
    }
    if (gid < 8192) {
        const int lane = gid & 63;
        const int kidx = (gid >> 6) & 15;
        const int cg   = gid >> 10;
        const int n    = cg * 16 + (lane & 15);
        const int k0   = kidx * 32 + (lane >> 4) * 8;
        u16 v[8];
        #pragma unroll
        for (int j = 0; j < 8; ++j) v[j] = f2bf(W[(k0 + j) * SD + n]);
        *(s16x8*)(WF + (long)gid * 8) = *(const s16x8*)v;
    }
}

// Main: grid 256 x 512 thr (8 waves). Block = 64 rows x 128 N x 512 K.
// LDS: A rows bf16 swizzled (64 KB) + WF chunk ping-pong (2 x 32 KB).
// WF chunks staged by global_load_lds dwordx4 (coalesced 1 KB/instr, zero
// VGPR/VALU). Gather: wave-cooperative 1 KB/instr, wave-uniform miss skip.
// 4 barriers total.
__global__ __launch_bounds__(512, 2) void fused_kernel(
    const float* __restrict__ emb,            // [500000][512]
    const u16* __restrict__ WF,               // [8][16][64][8] bf16
    const int* __restrict__ slot,             // [16384]
    const int* __restrict__ hit,              // [16384] int32 bool
    float* __restrict__ feats_out)            // [16384][128]
{
    __shared__ __align__(16) char Al[BR * TD * 2];    // 64 KiB
    __shared__ __align__(16) char Wf[2][32768];       // 64 KiB

    const int tid  = threadIdx.x;
    const int w    = tid >> 6;
    const int lane = tid & 63;
    const int m0b  = blockIdx.x * BR;

    // ---- gather: wave w owns rows w*8..w*8+7, 1 KB contiguous per instr ----
    f32x4 rg[8][2];
    #pragma unroll
    for (int r = 0; r < 8; ++r) {
        const int grow = m0b + w * 8 + r;
        if (hit[grow]) {                       // wave-uniform branch
            const float* rp = emb + (long)slot[grow] * TD + lane * 4;
            rg[r][0] = *(const f32x4*)rp;
            rg[r][1] = *(const f32x4*)(rp + 256);
        } else {
            rg[r][0] = (f32x4){0.f, 0.f, 0.f, 0.f};
            rg[r][1] = (f32x4){0.f, 0.f, 0.f, 0.f};
        }
    }

    // ---- WF chunk stage: wave w covers cg=w; 4 glds16 per thread ----
    // LDS unit (w*4+s4)*64+lane <- WF unit (w*16 + c*4 + s4)*64 + lane.
#define GLDS(c, buf)                                                          \
    {                                                                         \
        _Pragma("unroll")                                                     \
        for (int s4 = 0; s4 < 4; ++s4)                                        \
            glds16(WF + ((long)(w * 16 + (c) * 4 + s4) * 64 + lane) * 8,      \
                   Wf[buf] + (w * 4 + s4) * 1024);                            \
    }

    GLDS(0, 0);
    GLDS(1, 1);

    // ---- A -> LDS (bf16, XOR-swizzled rows); waits gather, glds fly on ----
    #pragma unroll
    for (int r = 0; r < 8; ++r) {
        const int rowL = w * 8 + r;
        const int swz = (rowL & 7) << 4;
        const int b0 = (rowL << 10) | (lane << 3);
        *(u64*)(Al + (b0 ^ swz))         = pack4bf(rg[r][0]);
        *(u64*)(Al + ((b0 + 512) ^ swz)) = pack4bf(rg[r][1]);
    }

    // ---- compute identity: wave -> row-group g, N-half h ----
    const int g = w >> 1;
    const int h = w & 1;
    const int lr16 = lane & 15;
    const int kb   = lane >> 4;
    const int rowL = g * 16 + lr16;
    const int aswz = (rowL & 7) << 4;

    f32x4 acc[4];
    #pragma unroll
    for (int t = 0; t < 4; ++t) acc[t] = (f32x4){0.f, 0.f, 0.f, 0.f};

#define COMPUTE(c, buf)                                                       \
    {                                                                         \
        _Pragma("unroll")                                                     \
        for (int s4 = 0; s4 < 4; ++s4) {                                      \
            const int abyte = ((rowL << 10) |                                 \
                               ((c) * 256 + s4 * 64 + kb * 16)) ^ aswz;       \
            const s16x8 a = *(const s16x8*)(Al + abyte);                      \
            _Pragma("unroll")                                                 \
            for (int t = 0; t < 4; ++t) {                                     \
                const s16x8 b = *(const s16x8*)(Wf[buf] +                     \
                    (((h * 4 + t) * 4 + s4) * 64 + lane) * 16);               \
                acc[t] = __builtin_amdgcn_mfma_f32_16x16x32_bf16(             \
                             a, b, acc[t], 0, 0, 0);                          \
            }                                                                 \
        }                                                                     \
    }

    __syncthreads();            // bar1: A + c0 + c1 resident
    COMPUTE(0, 0);
    __syncthreads();            // bar2: all waves done reading buf0
    GLDS(2, 0);                 // c2 -> buf0, overlaps compute c1
    COMPUTE(1, 1);
    __syncthreads();            // bar3: buf1 free; drains c2's glds
    GLDS(3, 1);                 // c3 -> buf1, overlaps compute c2
    COMPUTE(2, 0);
    __syncthreads();            // bar4: drains c3
    COMPUTE(3, 1);

#undef GLDS
#undef COMPUTE

    // ---- feats store: D row = kb*4+i, col = (h*4+t)*16 + lr16 ----
    #pragma unroll
    for (int t = 0; t < 4; ++t)
        #pragma unroll
        for (int i = 0; i < 4; ++i)
            feats_out[(long)(m0b + g * 16 + kb * 4 + i) * SD +
                      (h * 4 + t) * 16 + lr16] = acc[t][i];
}

extern "C" void kernel_launch(void* const* d_in, const int* in_sizes, int n_in,
                              void* d_out, int out_size, void* d_ws, size_t ws_size,
                              hipStream_t stream) {
    const float* cache_emb    = (const float*)d_in[0];
    const float* cache_logits = (const float*)d_in[1];
    const float* W            = (const float*)d_in[2];
    const int*   slot_idx     = (const int*)d_in[3];
    const int*   hitm         = (const int*)d_in[4];

    float* feats_out  = (float*)d_out;                       // 16384*128
    float* logits_out = (float*)d_out + (long)BATCH * SD;    // 16384*8

    u16* WF = (u16*)d_ws;                                    // 128 KiB

    prep_kernel<<<128, 256, 0, stream>>>(W, cache_logits, slot_idx, hitm,
                                         WF, logits_out);
    fused_kernel<<<BATCH / BR, 512, 0, stream>>>(cache_emb, WF,
                                                 slot_idx, hitm, feats_out);
}

// Round 13
// 14.984 us; speedup vs baseline: 1.1907x; 1.1907x over previous
//
#include <hip/hip_runtime.h>
#include <hip/hip_bf16.h>

#define TD 512
#define SD 128
#define NT 8
#define BATCH 16384
#define BR 64              // rows per block

typedef float f32x4 __attribute__((ext_vector_type(4)));
typedef short s16x8 __attribute__((ext_vector_type(8)));
typedef unsigned short u16;
typedef unsigned long long u64;

__device__ __forceinline__ u16 f2bf(float f) {
    return __builtin_bit_cast(u16, __float2bfloat16(f));   // RNE
}
__device__ __forceinline__ u64 pack4bf(f32x4 v) {
    u16 a[4];
    #pragma unroll
    for (int j = 0; j < 4; ++j) a[j] = f2bf(v[j]);
    return __builtin_bit_cast(u64, *(ushort4*)a);
}

// CHAMPION (R9/R11, 14.9/15.0 us). Single kernel. Grid 256 x 512 thr (8
// waves). Block = 64 rows x 128 N x 512 K.
// LDS: A rows bf16 swizzled (64 KB) + W-fragment ping-pong (2 x 32 KB).
// W staged per 128-K chunk: scalar f32 loads (L2-hot, hidden under gather)
// -> pack -> conflict-free ds_write_b128 in MFMA-B lane order.
// Gather: wave-cooperative, 1 KB contiguous per instr, wave-uniform miss
// skip. 4 barriers total.
__global__ __launch_bounds__(512, 2) void fused_kernel(
    const float* __restrict__ emb,            // [500000][512]
    const float* __restrict__ clogits,        // [500000][8]
    const float* __restrict__ W,              // [512][128]
    const int* __restrict__ slot,             // [16384]
    const int* __restrict__ hit,              // [16384] int32 bool
    float* __restrict__ feats_out,            // [16384][128]
    float* __restrict__ logits_out)           // [16384][8]
{
    __shared__ __align__(16) char Al[BR * TD * 2];    // 64 KiB
    __shared__ __align__(16) char Wf[2][32768];       // 64 KiB

    const int tid  = threadIdx.x;
    const int w    = tid >> 6;
    const int lane = tid & 63;
    const int m0b  = blockIdx.x * BR;

    // ---- gather: wave w owns rows w*8..w*8+7, 1 KB contiguous per instr ----
    f32x4 rg[8][2];
    #pragma unroll
    for (int r = 0; r < 8; ++r) {
        const int grow = m0b + w * 8 + r;
        if (hit[grow]) {                       // wave-uniform branch
            const float* rp = emb + (long)slot[grow] * TD + lane * 4;
            rg[r][0] = *(const f32x4*)rp;
            rg[r][1] = *(const f32x4*)(rp + 256);
        } else {
            rg[r][0] = (f32x4){0.f, 0.f, 0.f, 0.f};
            rg[r][1] = (f32x4){0.f, 0.f, 0.f, 0.f};
        }
    }

    // ---- W chunk c slot map: s = tid + 512*i -> lane=s&63, ks=(s>>6)&3,
    //      cg=(s>>8)&7; value j: W[c*128 + ks*32 + ((s>>4)&3)*8 + j][cg*16+(s&15)]
#define STAGE_LOAD(c, WS)                                                     \
    {                                                                         \
        _Pragma("unroll")                                                     \
        for (int i = 0; i < 4; ++i) {                                         \
            const int s = tid + 512 * i;                                      \
            const int kbase = (c) * 128 + ((s >> 6) & 3) * 32 +               \
                              ((s >> 4) & 3) * 8;                             \
            const int n = ((s >> 8) & 7) * 16 + (s & 15);                     \
            _Pragma("unroll")                                                 \
            for (int j = 0; j < 8; ++j)                                       \
                WS[i * 8 + j] = W[(kbase + j) * SD + n];                      \
        }                                                                     \
    }

#define STAGE_WRITE(buf, WS)                                                  \
    {                                                                         \
        _Pragma("unroll")                                                     \
        for (int i = 0; i < 4; ++i) {                                         \
            u16 v[8];                                                         \
            _Pragma("unroll")                                                 \
            for (int j = 0; j < 8; ++j) v[j] = f2bf(WS[i * 8 + j]);           \
            *(s16x8*)(Wf[buf] + (tid + 512 * i) * 16) = *(const s16x8*)v;     \
        }                                                                     \
    }

    // ---- logits (issued alongside; 1 per thread) ----
    const int lrow = m0b + (tid >> 3);
    const int lj   = tid & 7;
    float lv = 0.f;
    if (hit[lrow]) lv = clogits[(long)slot[lrow] * NT + lj];

    float wsA[32], wsB[32];
    STAGE_LOAD(0, wsA);

    // ---- A -> LDS (bf16, XOR-swizzled rows) ----
    #pragma unroll
    for (int r = 0; r < 8; ++r) {
        const int rowL = w * 8 + r;
        const int swz = (rowL & 7) << 4;
        const int b0 = (rowL << 10) | (lane << 3);
        *(u64*)(Al + (b0 ^ swz))         = pack4bf(rg[r][0]);
        *(u64*)(Al + ((b0 + 512) ^ swz)) = pack4bf(rg[r][1]);
    }
    logits_out[(long)lrow * NT + lj] = lv;

    STAGE_WRITE(0, wsA);
    STAGE_LOAD(1, wsB);

    // ---- compute identity: wave -> row-group g, N-half h ----
    const int g = w >> 1;
    const int h = w & 1;
    const int lr16 = lane & 15;
    const int kb   = lane >> 4;
    const int rowL = g * 16 + lr16;
    const int aswz = (rowL & 7) << 4;

    f32x4 acc[4];
    #pragma unroll
    for (int t = 0; t < 4; ++t) acc[t] = (f32x4){0.f, 0.f, 0.f, 0.f};

#define COMPUTE(c, buf)                                                       \
    {                                                                         \
        _Pragma("unroll")                                                     \
        for (int s4 = 0; s4 < 4; ++s4) {                                      \
            const int abyte = ((rowL << 10) |                                 \
                               ((c) * 256 + s4 * 64 + kb * 16)) ^ aswz;       \
            const s16x8 a = *(const s16x8*)(Al + abyte);                      \
            _Pragma("unroll")                                                 \
            for (int t = 0; t < 4; ++t) {                                     \
                const s16x8 b = *(const s16x8*)(Wf[buf] +                     \
                    (((h * 4 + t) * 4 + s4) * 64 + lane) * 16);               \
                acc[t] = __builtin_amdgcn_mfma_f32_16x16x32_bf16(             \
                             a, b, acc[t], 0, 0, 0);                          \
            }                                                                 \
        }                                                                     \
    }

    __syncthreads();            // bar1: A + frag c0 ready
    COMPUTE(0, 0);
    STAGE_WRITE(1, wsB);
    STAGE_LOAD(2, wsA);
    __syncthreads();            // bar2: frag c1 ready; c0 reads done
    COMPUTE(1, 1);
    STAGE_WRITE(0, wsA);        // c2 -> bufA (last read ended at bar2)
    STAGE_LOAD(3, wsB);
    __syncthreads();            // bar3: frag c2 ready; c1 reads done
    COMPUTE(2, 0);
    STAGE_WRITE(1, wsB);        // c3 -> bufB (last read ended at bar3)
    __syncthreads();            // bar4: frag c3 ready
    COMPUTE(3, 1);

#undef STAGE_LOAD
#undef STAGE_WRITE
#undef COMPUTE

    // ---- feats store: D row = kb*4+i, col = (h*4+t)*16 + lr16 ----
    #pragma unroll
    for (int t = 0; t < 4; ++t)
        #pragma unroll
        for (int i = 0; i < 4; ++i)
            feats_out[(long)(m0b + g * 16 + kb * 4 + i) * SD +
                      (h * 4 + t) * 16 + lr16] = acc[t][i];
}

extern "C" void kernel_launch(void* const* d_in, const int* in_sizes, int n_in,
                              void* d_out, int out_size, void* d_ws, size_t ws_size,
                              hipStream_t stream) {
    const float* cache_emb    = (const float*)d_in[0];
    const float* cache_logits = (const float*)d_in[1];
    const float* W            = (const float*)d_in[2];
    const int*   slot_idx     = (const int*)d_in[3];
    const int*   hitm         = (const int*)d_in[4];

    float* feats_out  = (float*)d_out;                       // 16384*128
    float* logits_out = (float*)d_out + (long)BATCH * SD;    // 16384*8

    fused_kernel<<<BATCH / BR, 512, 0, stream>>>(cache_emb, cache_logits, W,
                                                 slot_idx, hitm,
                                                 feats_out, logits_out);
}